// Round 4
// baseline (997.148 us; speedup 1.0000x reference)
//
#include <hip/hip_runtime.h>
#include <stdint.h>

#define BATCH 8192
#define DIM   1024            // elements per row; fp8 => also bytes per row
#define BT    256             // output tile: BT x BT
#define NT2   32              // 8192 / 256 tiles per dimension
#define NBLK  528             // NT2*(NT2+1)/2 upper-triangle blocks per feature
#define CPX   66              // NBLK / 8 : blocks per XCD chunk (bijective swizzle)
#define SBUF  (BT * 128)      // bytes per LDS tile buffer (32 KB)
#define PANEL ((size_t)BATCH * 128)   // bytes per K-block panel in Fn layout (1 MB)

#define FSCALE 8.0f                          // pre-scale before fp8 quant
#define EXPF   (2.0f / (FSCALE * FSCALE))    // exp(2*dot) = exp(acc * EXPF)

typedef int   intx4   __attribute__((ext_vector_type(4)));
typedef int   intx8   __attribute__((ext_vector_type(8)));
typedef float floatx4 __attribute__((ext_vector_type(4)));

__device__ __forceinline__ void async_ld16(const void* g, void* l) {
    __builtin_amdgcn_global_load_lds(
        (__attribute__((address_space(1))) void*)(void*)g,
        (__attribute__((address_space(3))) void*)l,
        16, 0, 0);
}

// ------------- row L2-normalize: fp32 -> fp8 e4m3 (x FSCALE) -------------
// Output layout is K-BLOCKED: Fn[f][kb=e>>7][row][e&127] so that the sim
// kernel's global_load_lds covers 1024 CONTIGUOUS bytes per instruction
// (8 consecutive rows' 128-B K-slices). Round-2 evidence: the old row-major
// layout made every staging instr 8 disjoint 128-B segments at 1-KB stride,
// pinning per-CU load throughput at 6.9 B/cyc (vs 23 B/cyc proven by m97's
// contiguous staging) regardless of pipelining.
__global__ __launch_bounds__(256) void norm_kernel(const float* __restrict__ text,
                                                   const float* __restrict__ image,
                                                   unsigned char* __restrict__ out) {
    const int fsel = blockIdx.y;
    const float* in = fsel ? image : text;
    unsigned char* o = out + (size_t)fsel * BATCH * DIM;
    const int row = blockIdx.x;
    const int t   = threadIdx.x;
    const float4* src = (const float4*)(in + (size_t)row * DIM);
    float4 v = src[t];
    float ss = v.x * v.x + v.y * v.y + v.z * v.z + v.w * v.w;
    #pragma unroll
    for (int m = 32; m >= 1; m >>= 1) ss += __shfl_xor(ss, m);
    __shared__ float red[4];
    if ((t & 63) == 0) red[t >> 6] = ss;
    __syncthreads();
    const float n2  = red[0] + red[1] + red[2] + red[3];
    const float inv = FSCALE / fmaxf(sqrtf(n2), 1e-12f);
    // pack 4 e4m3 bytes (gfx950: OCP e4m3fn), byte i = element t*4+i
    int p = __builtin_amdgcn_cvt_pk_fp8_f32(v.x * inv, v.y * inv, 0, false);
    p     = __builtin_amdgcn_cvt_pk_fp8_f32(v.z * inv, v.w * inv, p, true);
    // element byte index e = t*4: kb = t>>5, offset within panel row = (4t)&127
    ((int*)(o + (size_t)(t >> 5) * PANEL + (size_t)row * 128))[t & 31] = p;
}

// -------- fused symmetric sim GEMM (MX-fp8, unit scales) + exp + dual sum --------
// 256x256 tiles (NT2=32), 8 waves (2 row-halves x 4 col-quarters), BK=128 via
// mfma_scale_f32_16x16x128_f8f6f4, double-buffered LDS + counted vmcnt(8).
// ROUND-3 BUG FIX: __launch_bounds__(512,2) capped the allocator at 128
// VGPR/wave while acc[8][4] alone is 128 f32 -> the accumulator spilled to
// scratch (WRITE_SIZE 8 MB -> 1.09 GB, FETCH 47 MB -> 1.9 GB, MfmaUtil 3%).
// LDS (128 KB) limits to 1 block/CU anyway, so min-waves=2 bought nothing.
// Now (512,1): 256 VGPR cap, m201-precedent config (256^2, 8 waves, dbuf) fits.
// Epilogue: NO global atomics. Block (bi,bj) owns slot bj for row-partials and
// slot bi for col-partials -> exact disjoint cover of P[f][u][slot][g].
__global__ __launch_bounds__(512, 1) void sim_kernel(const unsigned char* __restrict__ F,
                                                     const int* __restrict__ label,
                                                     float* __restrict__ P) {
    // bijective XCD chunk swizzle: 528 = 8 * 66; consecutive local indices
    // (same XCD) walk consecutive triangular tiles -> shared A-panels in L2.
    int l = ((blockIdx.x & 7) * CPX) + (blockIdx.x >> 3);
    int bi = 0;
    for (;;) { const int wdt = NT2 - bi; if (l < wdt) break; l -= wdt; ++bi; }
    const int bj   = bi + l;
    const bool diag = (bi == bj);

    const int f = blockIdx.z;
    const unsigned char* A = F + (size_t)f * BATCH * DIM;

    const int rowTile = bi * BT;
    const int colTile = bj * BT;

    // 256 rows x 128 K-bytes per tile buffer, double-buffered.
    // 16-B chunk swizzle: chunk c of row r stored at slot c ^ (r&7).
    __shared__ __align__(16) unsigned char As[2][SBUF];
    __shared__ __align__(16) unsigned char Bs[2][SBUF];

    const int tid  = threadIdx.x;
    const int lane = tid & 63;
    const int wave = tid >> 6;          // 0..7
    const int wr   = wave >> 2;         // row half  (0..1) -> rows wr*128..+128
    const int wc   = wave & 3;          // col quarter (0..3) -> cols wc*64..+64
    const int quad = lane >> 4;
    const int cl   = lane & 15;

    // staging: waves 0-3 stage A (64 rows each), waves 4-7 stage B.
    // per instr: 8 rows x 128 B = 1024 contiguous bytes in the K-blocked layout;
    // per-lane source pre-swizzled (chunk (l&7)^(l>>3)), LDS dest linear.
    const bool isB = wave >= 4;
    const int  sw  = wave & 3;
    const int  laneOff = ((lane >> 3) << 7) + ((((lane & 7) ^ (lane >> 3))) << 4);
    const unsigned char* gsrc = A + ((size_t)((isB ? colTile : rowTile) + sw * 64) << 7) + laneOff;
    unsigned char* lbase = (isB ? Bs[0] : As[0]) + sw * 8192;

    floatx4 acc[8][4];
    const floatx4 z4 = {0.f, 0.f, 0.f, 0.f};
    #pragma unroll
    for (int mi = 0; mi < 8; ++mi)
        #pragma unroll
        for (int ni = 0; ni < 4; ++ni) acc[mi][ni] = z4;

    // frag read slots (un-swizzle): lane reads 16-B chunks 2q, 2q+1 of its row
    const int h  = cl & 7;
    const int s0 = ((2 * quad) ^ h) * 16;
    const int s1 = ((2 * quad + 1) ^ h) * 16;

    // ---- prologue: stage K-block 0 into buffer 0 (8 loads/thread in flight) ----
    #pragma unroll
    for (int t = 0; t < 8; ++t)
        async_ld16(gsrc + (size_t)t * 1024, lbase + t * 1024);
    gsrc += PANEL;

    for (int kb = 0; kb < 8; ++kb) {
        const int cur = kb & 1;
        const int nxt = cur ^ 1;
        if (kb < 7) {
            // prefetch K-block kb+1 into the buffer not read this iter
            // (trailing barrier of iter kb-1 guarantees it is free).
            #pragma unroll
            for (int t = 0; t < 8; ++t)
                async_ld16(gsrc + (size_t)t * 1024, lbase + nxt * SBUF + t * 1024);
            gsrc += PANEL;
            asm volatile("s_waitcnt vmcnt(8)" ::: "memory");   // this wave's kb loads
        } else {
            asm volatile("s_waitcnt vmcnt(0)" ::: "memory");
        }
        __builtin_amdgcn_s_barrier();        // all waves' kb data in LDS
        __builtin_amdgcn_sched_barrier(0);   // keep ds_reads below the barrier

        const unsigned char* aR = As[cur] + (size_t)(wr * 128 + cl) * 128;
        const unsigned char* bR = Bs[cur] + (size_t)(wc * 64  + cl) * 128;

        intx8 bf[4];                         // B frags resident (32 VGPR)
        #pragma unroll
        for (int ni = 0; ni < 4; ++ni) {
            const unsigned char* r = bR + ni * 2048;
            intx4 lo = *(const intx4*)(r + s0);
            intx4 hi = *(const intx4*)(r + s1);
            bf[ni][0] = lo[0]; bf[ni][1] = lo[1]; bf[ni][2] = lo[2]; bf[ni][3] = lo[3];
            bf[ni][4] = hi[0]; bf[ni][5] = hi[1]; bf[ni][6] = hi[2]; bf[ni][7] = hi[3];
        }
        __builtin_amdgcn_s_setprio(1);
        #pragma unroll
        for (int mi = 0; mi < 8; ++mi) {     // A frags streamed (8 VGPR each)
            const unsigned char* r = aR + mi * 2048;
            intx4 lo = *(const intx4*)(r + s0);
            intx4 hi = *(const intx4*)(r + s1);
            intx8 af;
            af[0] = lo[0]; af[1] = lo[1]; af[2] = lo[2]; af[3] = lo[3];
            af[4] = hi[0]; af[5] = hi[1]; af[6] = hi[2]; af[7] = hi[3];
            #pragma unroll
            for (int ni = 0; ni < 4; ++ni)
                acc[mi][ni] = __builtin_amdgcn_mfma_scale_f32_16x16x128_f8f6f4(
                    af, bf[ni], acc[mi][ni],
                    0, 0,                     // cbsz=fp8(e4m3), blgp=fp8(e4m3)
                    0, 0x7F7F7F7F,            // scale_a = 2^0
                    0, 0x7F7F7F7F);           // scale_b = 2^0
        }
        __builtin_amdgcn_s_setprio(0);
        __builtin_amdgcn_sched_barrier(0);   // keep reads/MFMA above the barrier
        __builtin_amdgcn_s_barrier();        // buf[cur] free for next prefetch
    }

    // ---- epilogue: e = exp(acc * EXPF), eye mask, block-local LDS reduction,
    //      conflict-free partial-sum stores (no atomics, no memset) ----
    // red layout (floats, in As[0]; last iter read As[1], writes are safe):
    //   [0..1024)    rowR: idx = wc*256 + rowLoc
    //   [1024..2048) rowN
    //   [2048..2560) colR: idx = wr*256 + colLoc
    //   [2560..3072) colN
    // every entry written by exactly one lane -> plain ds_write, no init.
    float* red = (float*)As;

    int   colg[4], colLoc[4];
    float wRc[4];
    #pragma unroll
    for (int ni = 0; ni < 4; ++ni) {
        colLoc[ni] = wc * 64 + ni * 16 + cl;
        colg[ni]   = colTile + colLoc[ni];
        wRc[ni]    = (label[colg[ni]] != 0) ? 1.0f : 0.0f;
    }

    float colRa[4] = {0.f, 0.f, 0.f, 0.f};
    float colNa[4] = {0.f, 0.f, 0.f, 0.f};

    #pragma unroll
    for (int mi = 0; mi < 8; ++mi) {
        const int rowLocB = wr * 128 + mi * 16 + quad * 4;   // C/D: row=quad*4+reg
        #pragma unroll
        for (int r = 0; r < 4; ++r) {
            const int rowLoc = rowLocB + r;
            const int rowg   = rowTile + rowLoc;
            const float wRr  = (label[rowg] != 0) ? 1.0f : 0.0f;
            float pR = 0.f, pN = 0.f;
            #pragma unroll
            for (int ni = 0; ni < 4; ++ni) {
                float c = acc[mi][ni][r];
                float e = __expf(c * EXPF);
                if (diag) e = (rowg == colg[ni]) ? 0.0f : e;      // eye mask
                pR += wRc[ni] * e;
                pN += (1.0f - wRc[ni]) * e;
                colRa[ni] += wRr * e;
                colNa[ni] += (1.0f - wRr) * e;
            }
            #pragma unroll
            for (int m = 1; m < 16; m <<= 1) {      // reduce 16 cl lanes
                pR += __shfl_xor(pR, m);
                pN += __shfl_xor(pN, m);
            }
            if (cl == 0) {
                red[wc * 256 + rowLoc]        = pR;
                red[1024 + wc * 256 + rowLoc] = pN;
            }
        }
    }

    if (!diag) {
        #pragma unroll
        for (int ni = 0; ni < 4; ++ni) {
            float cR = colRa[ni], cN = colNa[ni];
            cR += __shfl_xor(cR, 16); cN += __shfl_xor(cN, 16);  // reduce quads
            cR += __shfl_xor(cR, 32); cN += __shfl_xor(cN, 32);
            if (quad == 0) {
                red[2048 + wr * 256 + colLoc[ni]] = cR;
                red[2560 + wr * 256 + colLoc[ni]] = cN;
            }
        }
    }

    __syncthreads();
    // P layout: [f][u(R=0,N=1)][slot 0..31][g 0..8191]
    float* Pr = P + ((size_t)f * 2 + 0) * (size_t)NT2 * BATCH;
    float* Pn = P + ((size_t)f * 2 + 1) * (size_t)NT2 * BATCH;
    if (tid < 256) {
        float sR = red[tid] + red[256 + tid] + red[512 + tid] + red[768 + tid];
        float sN = red[1024 + tid] + red[1280 + tid] + red[1536 + tid] + red[1792 + tid];
        Pr[(size_t)bj * BATCH + rowTile + tid] = sR;
        Pn[(size_t)bj * BATCH + rowTile + tid] = sN;
        if (!diag) {
            Pr[(size_t)bi * BATCH + colTile + tid] = red[2048 + tid] + red[2304 + tid];
            Pn[(size_t)bi * BATCH + colTile + tid] = red[2560 + tid] + red[2816 + tid];
        }
    }
}

// -------- final: 32-slot partial reduce + per-row loss + global reduce --------
__global__ __launch_bounds__(256) void loss_kernel(const float* __restrict__ P,
                                                   const int* __restrict__ label,
                                                   float* __restrict__ out) {
    const int idx = blockIdx.x * 256 + threadIdx.x;   // 0..16383 = (f, i)
    const int f = idx >> 13;
    const int i = idx & (BATCH - 1);
    const int lab = label[i];
    const float* Pr = P + ((size_t)f * 2 + 0) * (size_t)NT2 * BATCH;
    const float* Pn = Pr + (size_t)NT2 * BATCH;
    float sR = 0.f, sN = 0.f;
    #pragma unroll 8
    for (int s = 0; s < NT2; ++s) {
        sR += Pr[(size_t)s * BATCH + i];
        sN += Pn[(size_t)s * BATCH + i];
    }
    const float own = lab ? sR : sN;
    const float oth = lab ? sN : sR;
    float t = -logf(own / (own + oth) + 1e-8f) * (1.0f / 4096.0f);
    #pragma unroll
    for (int m = 32; m >= 1; m >>= 1) t += __shfl_xor(t, m);
    __shared__ float red[4];
    if ((threadIdx.x & 63) == 0) red[threadIdx.x >> 6] = t;
    __syncthreads();
    if (threadIdx.x == 0) atomicAdd(out, red[0] + red[1] + red[2] + red[3]);
}

extern "C" void kernel_launch(void* const* d_in, const int* in_sizes, int n_in,
                              void* d_out, int out_size, void* d_ws, size_t ws_size,
                              hipStream_t stream) {
    const float* text  = (const float*)d_in[0];
    const float* image = (const float*)d_in[1];
    const int*   label = (const int*)d_in[2];
    float* out = (float*)d_out;

    // workspace: Fn[2][8][8192][128] fp8 (16 MB), then P[2][2][32][8192] f32 (4 MB)
    unsigned char* Fn = (unsigned char*)d_ws;
    float* P = (float*)((char*)d_ws + (size_t)2 * BATCH * DIM);

    hipMemsetAsync(out, 0, sizeof(float), stream);

    dim3 ngrid(BATCH, 2);
    norm_kernel<<<ngrid, 256, 0, stream>>>(text, image, Fn);

    dim3 grid(NBLK, 1, 2);
    sim_kernel<<<grid, 512, 0, stream>>>(Fn, label, P);

    loss_kernel<<<(2 * BATCH) / 256, 256, 0, stream>>>(P, label, out);
}

// Round 5
// 338.045 us; speedup vs baseline: 2.9498x; 2.9498x over previous
//
#include <hip/hip_runtime.h>
#include <stdint.h>

#define BATCH 8192
#define DIM   1024            // elements per row; fp8 => also bytes per row
#define NTILE 64              // 8192 / 128 tiles per dimension
#define MAXB  292             // max tiles per XCD band
#define GRIDX (8 * MAXB)      // padded x-grid; blocks past band size exit
#define PANEL ((size_t)BATCH * 128)   // bytes per K-block panel in Fn layout (1 MB)

#define FSCALE 8.0f                          // pre-scale before fp8 quant
#define EXPF   (2.0f / (FSCALE * FSCALE))    // exp(2*dot) = exp(acc * EXPF)

#define TILEB 16384                          // bytes per 128x128 LDS tile buffer

typedef int   intx4   __attribute__((ext_vector_type(4)));
typedef int   intx8   __attribute__((ext_vector_type(8)));
typedef float floatx4 __attribute__((ext_vector_type(4)));

__device__ __forceinline__ void async_ld16(const void* g, void* l) {
    __builtin_amdgcn_global_load_lds(
        (__attribute__((address_space(1))) void*)(void*)g,
        (__attribute__((address_space(3))) void*)l,
        16, 0, 0);
}

// ------------- row L2-normalize: fp32 -> fp8 e4m3 (x FSCALE) -------------
// Output layout is K-BLOCKED: Fn[f][kb=e>>7][row][e&127] so each sim-kernel
// global_load_lds instruction covers 1024 CONTIGUOUS bytes (8 consecutive
// rows' 128-B K-slices). Round-2 evidence: row-major layout made every
// staging instr 8 disjoint 128-B segments at 1-KB stride -> ~6.9 B/cyc/CU
// effective staging rate (vs 23 B/cyc proven contiguous), schedule-invariant.
__global__ __launch_bounds__(256) void norm_kernel(const float* __restrict__ text,
                                                   const float* __restrict__ image,
                                                   unsigned char* __restrict__ out) {
    const int fsel = blockIdx.y;
    const float* in = fsel ? image : text;
    unsigned char* o = out + (size_t)fsel * BATCH * DIM;
    const int row = blockIdx.x;
    const int t   = threadIdx.x;
    const float4* src = (const float4*)(in + (size_t)row * DIM);
    float4 v = src[t];
    float ss = v.x * v.x + v.y * v.y + v.z * v.z + v.w * v.w;
    #pragma unroll
    for (int m = 32; m >= 1; m >>= 1) ss += __shfl_xor(ss, m);
    __shared__ float red[4];
    if ((t & 63) == 0) red[t >> 6] = ss;
    __syncthreads();
    const float n2  = red[0] + red[1] + red[2] + red[3];
    const float inv = FSCALE / fmaxf(sqrtf(n2), 1e-12f);
    // pack 4 e4m3 bytes (gfx950: OCP e4m3fn), byte i = element t*4+i
    int p = __builtin_amdgcn_cvt_pk_fp8_f32(v.x * inv, v.y * inv, 0, false);
    p     = __builtin_amdgcn_cvt_pk_fp8_f32(v.z * inv, v.w * inv, p, true);
    // element byte e = 4t: kb = t>>5, int index within 128-B panel row = t&31
    ((int*)(o + (size_t)(t >> 5) * PANEL + (size_t)row * 128))[t & 31] = p;
}

// -------- fused symmetric sim GEMM (MX-fp8, unit scales) + exp + dual sum --------
// ROUND-5: exact round-2 skeleton (256 thr, 128^2 tiles, 248 VGPR, no spills)
// with ONE change: staging reads the K-blocked Fn layout, so each
// global_load_lds is a single contiguous 1-KB span (isolated test of the
// transaction-fragmentation theory). Rounds 3/4's 512-thread 256^2 variant is
// abandoned: 512-thread blocks compile to a 128-VGPR cap on this toolchain
// (launch_bounds-invariant) and acc[8][4] spills to scratch (3 GB hbm_bytes).
// Epilogue: NO global atomics. Block (bi,bj) owns slot bj for row-partials and
// slot bi for col-partials -> exact disjoint cover of P[f][u][slot][g].
__global__ __launch_bounds__(256) void sim_kernel(const unsigned char* __restrict__ F,
                                                  const int* __restrict__ label,
                                                  float* __restrict__ P) {
    // band tables: bj in [bs[x], be[x]); bn[x] = tiles in band
    const int bs[8] = {0, 23, 32, 40, 46, 51, 56, 60};
    const int be[8] = {23, 32, 40, 46, 51, 56, 60, 64};
    const int bn[8] = {276, 252, 292, 261, 245, 270, 234, 250};

    const int x = blockIdx.x & 7;       // XCD (round-robin dispatch heuristic)
    const int l = blockIdx.x >> 3;      // local index within band
    if (l >= bn[x]) return;             // padding block

    const int s = bs[x];
    const int w = be[x] - s;
    int bi, bj;
    const int nfull = s * w;
    if (l < nfull) {
        bi = l / w;
        bj = s + (l % w);
    } else {
        int l2 = l - nfull;
        int k = 0, width = w;
        while (l2 >= width) { l2 -= width; --width; ++k; }
        bi = s + k;
        bj = bi + l2;
    }
    const bool diag = (bi == bj);

    const int f = blockIdx.z;
    const unsigned char* A = F + (size_t)f * BATCH * DIM;

    const int rowTile = bi * 128;
    const int colTile = bj * 128;

    // two 128x128 tile buffers per operand (double buffer), 16-B chunk swizzle:
    // chunk c of row r stored at slot c ^ (r&7)  -> conflict-free b128 frag reads.
    __shared__ __align__(16) unsigned char As[2][TILEB];
    __shared__ __align__(16) unsigned char Bs[2][TILEB];

    const int tid  = threadIdx.x;
    const int lane = tid & 63;
    const int wave = tid >> 6;
    const int wm   = wave >> 1;        // 2x2 wave grid over the 128x128 tile
    const int wn   = wave & 1;
    const int quad = lane >> 4;
    const int cl   = lane & 15;

    // staging: issue t covers rows wave*32 + t*8 .. +8; lane -> row lane>>3,
    // LDS slot lane&7 (HW: dest = base + lane*16), global chunk = slot ^ (row&7).
    // K-blocked layout: row stride = 128 B -> the 64 lanes of one instruction
    // span exactly 1024 contiguous bytes (permuted within each row's 128 B).
    const int sRowOff = lane >> 3;            // 0..7
    const int chunk   = (lane & 7) ^ sRowOff; // (row&7) == sRowOff
    const unsigned char* gA = A + (size_t)(rowTile + wave * 32 + sRowOff) * 128 + chunk * 16;
    const unsigned char* gB = A + (size_t)(colTile + wave * 32 + sRowOff) * 128 + chunk * 16;
    unsigned char* lA = As[0] + wave * 32 * 128 + lane * 16;
    unsigned char* lB = Bs[0] + wave * 32 * 128 + lane * 16;

    floatx4 acc[4][4];
    const floatx4 z4 = {0.f, 0.f, 0.f, 0.f};
    #pragma unroll
    for (int mi = 0; mi < 4; ++mi)
        #pragma unroll
        for (int ni = 0; ni < 4; ++ni) acc[mi][ni] = z4;

    // frag read slots (un-swizzle): lane reads 16-B chunks 2q and 2q+1 of its row
    const int h  = cl & 7;
    const int s0 = ((2 * quad) ^ h) * 16;
    const int s1 = ((2 * quad + 1) ^ h) * 16;
    const unsigned char* aRow = As[0] + (size_t)(wm * 64 + cl) * 128;
    const unsigned char* bRow = Bs[0] + (size_t)(wn * 64 + cl) * 128;

    // ---- prologue: stage K-block 0 into buffer 0 (8 loads/wave in flight) ----
    #pragma unroll
    for (int t = 0; t < 4; ++t) {
        async_ld16(gA + (size_t)t * 1024, lA + t * 1024);
        async_ld16(gB + (size_t)t * 1024, lB + t * 1024);
    }
    gA += PANEL; gB += PANEL;

    #pragma unroll
    for (int kb = 0; kb < 8; ++kb) {
        const int cur = kb & 1;
        const int nxt = cur ^ 1;
        if (kb < 7) {
            // prefetch K-block kb+1 into the buffer not read this iter
            // (trailing barrier of iter kb-1 guarantees it is free).
            #pragma unroll
            for (int t = 0; t < 4; ++t) {
                async_ld16(gA + (size_t)t * 1024, lA + nxt * TILEB + t * 1024);
                async_ld16(gB + (size_t)t * 1024, lB + nxt * TILEB + t * 1024);
            }
            gA += PANEL; gB += PANEL;
            asm volatile("s_waitcnt vmcnt(8)" ::: "memory");   // this wave's kb loads
        } else {
            asm volatile("s_waitcnt vmcnt(0)" ::: "memory");
        }
        __builtin_amdgcn_s_barrier();        // all waves' kb data in LDS
        __builtin_amdgcn_sched_barrier(0);   // keep ds_reads below the barrier

        intx8 af[4], bf[4];
        #pragma unroll
        for (int mi = 0; mi < 4; ++mi) {
            const unsigned char* r = aRow + cur * TILEB + mi * 16 * 128;
            intx4 lo = *(const intx4*)(r + s0);
            intx4 hi = *(const intx4*)(r + s1);
            af[mi][0] = lo[0]; af[mi][1] = lo[1]; af[mi][2] = lo[2]; af[mi][3] = lo[3];
            af[mi][4] = hi[0]; af[mi][5] = hi[1]; af[mi][6] = hi[2]; af[mi][7] = hi[3];
        }
        #pragma unroll
        for (int ni = 0; ni < 4; ++ni) {
            const unsigned char* r = bRow + cur * TILEB + ni * 16 * 128;
            intx4 lo = *(const intx4*)(r + s0);
            intx4 hi = *(const intx4*)(r + s1);
            bf[ni][0] = lo[0]; bf[ni][1] = lo[1]; bf[ni][2] = lo[2]; bf[ni][3] = lo[3];
            bf[ni][4] = hi[0]; bf[ni][5] = hi[1]; bf[ni][6] = hi[2]; bf[ni][7] = hi[3];
        }
        __builtin_amdgcn_s_setprio(1);
        #pragma unroll
        for (int mi = 0; mi < 4; ++mi)
            #pragma unroll
            for (int ni = 0; ni < 4; ++ni)
                acc[mi][ni] = __builtin_amdgcn_mfma_scale_f32_16x16x128_f8f6f4(
                    af[mi], bf[ni], acc[mi][ni],
                    0, 0,                     // cbsz=fp8(e4m3), blgp=fp8(e4m3)
                    0, 0x7F7F7F7F,            // scale_a = 2^0
                    0, 0x7F7F7F7F);           // scale_b = 2^0
        __builtin_amdgcn_s_setprio(0);
        __builtin_amdgcn_sched_barrier(0);   // keep reads/MFMA above the barrier
        __builtin_amdgcn_s_barrier();        // buf[cur] free for next prefetch
    }

    // ---- epilogue: e = exp(acc * EXPF), eye mask, block-local LDS
    //      reduction, then conflict-free partial-sum stores (no atomics) ----
    __syncthreads();                      // all frag reads done; As reusable
    float* red = (float*)As;
    // layout (floats): [0..256)   rowR, indexed wn*128 + rowLoc
    //                  [256..512) rowN, indexed wn*128 + rowLoc
    //                  [512..768) colR, indexed wm*128 + colLoc
    //                  [768..1024) colN, indexed wm*128 + colLoc
    // every entry written by exactly one lane -> plain ds_write, no init.

    int   colg[4], colLoc[4];
    float wRc[4];                        // col label weight (row-part bucket)
    #pragma unroll
    for (int ni = 0; ni < 4; ++ni) {
        colLoc[ni] = wn * 64 + ni * 16 + cl;
        colg[ni]   = colTile + colLoc[ni];
        wRc[ni]    = (label[colg[ni]] != 0) ? 1.0f : 0.0f;
    }

    float colR[4] = {0.f, 0.f, 0.f, 0.f};
    float colN[4] = {0.f, 0.f, 0.f, 0.f};

    #pragma unroll
    for (int mi = 0; mi < 4; ++mi) {
        const int rowLocB = wm * 64 + mi * 16 + quad * 4;   // C/D: row=quad*4+reg
        #pragma unroll
        for (int r = 0; r < 4; ++r) {
            const int rowLoc = rowLocB + r;
            const int rowg   = rowTile + rowLoc;
            const float wRr  = (label[rowg] != 0) ? 1.0f : 0.0f;
            float pR = 0.f, pN = 0.f;
            #pragma unroll
            for (int ni = 0; ni < 4; ++ni) {
                float c = acc[mi][ni][r];
                float e = __expf(c * EXPF);
                if (diag) e = (rowg == colg[ni]) ? 0.0f : e;      // eye mask
                pR += wRc[ni] * e;
                pN += (1.0f - wRc[ni]) * e;
                colR[ni] += wRr * e;
                colN[ni] += (1.0f - wRr) * e;
            }
            #pragma unroll
            for (int m = 1; m < 16; m <<= 1) {
                pR += __shfl_xor(pR, m);
                pN += __shfl_xor(pN, m);
            }
            if (cl == 0) {
                red[wn * 128 + rowLoc]       = pR;
                red[256 + wn * 128 + rowLoc] = pN;
            }
        }
    }

    if (!diag) {
        #pragma unroll
        for (int ni = 0; ni < 4; ++ni) {
            float cR = colR[ni], cN = colN[ni];
            cR += __shfl_xor(cR, 16); cN += __shfl_xor(cN, 16);
            cR += __shfl_xor(cR, 32); cN += __shfl_xor(cN, 32);
            if (quad == 0) {
                red[512 + wm * 128 + colLoc[ni]] = cR;
                red[768 + wm * 128 + colLoc[ni]] = cN;
            }
        }
    }

    __syncthreads();
    // P layout: [f][u(R=0,N=1)][slot 0..63][g 0..8191]
    float* Pr = P + ((size_t)f * 2 + 0) * (size_t)NTILE * BATCH;
    float* Pn = P + ((size_t)f * 2 + 1) * (size_t)NTILE * BATCH;
    if (tid < 128) {
        Pr[(size_t)bj * BATCH + rowTile + tid] = red[tid]       + red[128 + tid];
        Pn[(size_t)bj * BATCH + rowTile + tid] = red[256 + tid] + red[384 + tid];
        if (!diag) {
            Pr[(size_t)bi * BATCH + colTile + tid] = red[512 + tid] + red[640 + tid];
            Pn[(size_t)bi * BATCH + colTile + tid] = red[768 + tid] + red[896 + tid];
        }
    }
}

// -------- final: 64-slot partial reduce + per-row loss + global reduce --------
__global__ __launch_bounds__(256) void loss_kernel(const float* __restrict__ P,
                                                   const int* __restrict__ label,
                                                   float* __restrict__ out) {
    const int idx = blockIdx.x * 256 + threadIdx.x;   // 0..16383 = (f, i)
    const int f = idx >> 13;
    const int i = idx & (BATCH - 1);
    const int lab = label[i];
    const float* Pr = P + ((size_t)f * 2 + 0) * (size_t)NTILE * BATCH;
    const float* Pn = Pr + (size_t)NTILE * BATCH;
    float sR = 0.f, sN = 0.f;
    #pragma unroll 8
    for (int s = 0; s < NTILE; ++s) {
        sR += Pr[(size_t)s * BATCH + i];
        sN += Pn[(size_t)s * BATCH + i];
    }
    const float own = lab ? sR : sN;
    const float oth = lab ? sN : sR;
    float t = -logf(own / (own + oth) + 1e-8f) * (1.0f / 4096.0f);
    #pragma unroll
    for (int m = 32; m >= 1; m >>= 1) t += __shfl_xor(t, m);
    __shared__ float red[4];
    if ((threadIdx.x & 63) == 0) red[threadIdx.x >> 6] = t;
    __syncthreads();
    if (threadIdx.x == 0) atomicAdd(out, red[0] + red[1] + red[2] + red[3]);
}

extern "C" void kernel_launch(void* const* d_in, const int* in_sizes, int n_in,
                              void* d_out, int out_size, void* d_ws, size_t ws_size,
                              hipStream_t stream) {
    const float* text  = (const float*)d_in[0];
    const float* image = (const float*)d_in[1];
    const int*   label = (const int*)d_in[2];
    float* out = (float*)d_out;

    // workspace: Fn[2][8][8192][128] fp8 (16 MB), then P[2][2][64][8192] f32 (8 MB)
    unsigned char* Fn = (unsigned char*)d_ws;
    float* P = (float*)((char*)d_ws + (size_t)2 * BATCH * DIM);

    hipMemsetAsync(out, 0, sizeof(float), stream);

    dim3 ngrid(BATCH, 2);
    norm_kernel<<<ngrid, 256, 0, stream>>>(text, image, Fn);

    dim3 grid(GRIDX, 1, 2);
    sim_kernel<<<grid, 256, 0, stream>>>(Fn, label, P);

    loss_kernel<<<(2 * BATCH) / 256, 256, 0, stream>>>(P, label, out);
}

// Round 6
// 226.915 us; speedup vs baseline: 4.3944x; 1.4897x over previous
//
#include <hip/hip_runtime.h>
#include <stdint.h>

#define BATCH 8192
#define DIM   1024            // elements per row; fp8 => also bytes per row
#define NTILE 64              // 8192 / 128 tiles per dimension
#define MAXB  292             // max tiles per XCD band
#define GRIDX (8 * MAXB)      // padded x-grid; blocks past band size exit

#define FSZ   ((size_t)BATCH * DIM)   // bytes per feature in Fn (8 MB)
#define PAN   ((size_t)64 * 8192)     // bytes per K-block panel: 64 rowblks x 8 KB
#define OPB   8192                    // bytes per operand tile image (128 rows x 64 kB)
#define SBUF  8192                    // bytes per LDS tile buffer

#define FSCALE 8.0f                          // pre-scale before fp8 quant
#define EXPF   (2.0f / (FSCALE * FSCALE))    // exp(2*dot) = exp(acc * EXPF)

typedef int   intx4   __attribute__((ext_vector_type(4)));
typedef float floatx4 __attribute__((ext_vector_type(4)));
typedef long  longx2  __attribute__((ext_vector_type(2)));

__device__ __forceinline__ void async_ld16(const void* g, void* l) {
    __builtin_amdgcn_global_load_lds(
        (__attribute__((address_space(1))) void*)(void*)g,
        (__attribute__((address_space(3))) void*)l,
        16, 0, 0);
}

__device__ __forceinline__ longx2 as_l2(intx4 v) {
    longx2 r;
    __builtin_memcpy(&r, &v, 16);
    return r;
}

// ------------- row L2-normalize: fp32 -> fp8 e4m3 (x FSCALE) -------------
// Output is FRAG-PACKED for the sim kernel's 16x16x32 fp8 MFMA:
//   Fn[f][kb:16][rowblk:64][ g:8 ][ q:4 ][ cl:16 ][16 B]
// where the 16-B chunk of (row, kb, q) = k-bytes [q*8..q*8+8) ++ [32+q*8..+8)
// of that row's 64-B K-block. Staging is then a pure linear copy (1 KB
// contiguous per global_load_lds) and frag reads are contiguous-stride
// ds_read_b128 (conflict-free, no swizzle anywhere).
__global__ __launch_bounds__(256) void norm_kernel(const float* __restrict__ text,
                                                   const float* __restrict__ image,
                                                   unsigned char* __restrict__ out) {
    const int f = blockIdx.y;
    const float* in = f ? image : text;
    const int row = blockIdx.x;
    const int o   = threadIdx.x;        // output int index within the row, 0..255
    const int kb  = o >> 4;
    const int rem = o & 15;
    const int q   = rem >> 2;
    const int ks  = (rem >> 1) & 1;
    const int j   = rem & 1;
    // gathered input float4: elements e..e+3, e = kb*64 + ks*32 + q*8 + j*4
    const int fi = kb * 16 + ks * 8 + q * 2 + j;   // bijective over [0,256)
    float4 v = ((const float4*)(in + (size_t)row * DIM))[fi];
    float ss = v.x * v.x + v.y * v.y + v.z * v.z + v.w * v.w;
    #pragma unroll
    for (int m = 32; m >= 1; m >>= 1) ss += __shfl_xor(ss, m);
    __shared__ float red[4];
    if ((o & 63) == 0) red[o >> 6] = ss;
    __syncthreads();
    const float n2  = red[0] + red[1] + red[2] + red[3];
    const float inv = FSCALE / fmaxf(sqrtf(n2), 1e-12f);
    // pack 4 e4m3 bytes (gfx950: OCP e4m3fn)
    int p = __builtin_amdgcn_cvt_pk_fp8_f32(v.x * inv, v.y * inv, 0, false);
    p     = __builtin_amdgcn_cvt_pk_fp8_f32(v.z * inv, v.w * inv, p, true);
    const int rb = row >> 7, r = row & 127, g = r >> 4, cl = r & 15;
    const size_t off = (size_t)f * FSZ + (size_t)kb * PAN + (size_t)rb * OPB
                     + g * 1024 + q * 256 + cl * 16 + ks * 8 + j * 4;
    *(int*)(out + off) = p;
}

// -------- fused symmetric sim GEMM (fp8 K=32 MFMA) + exp + dual sum --------
// ROUND-6 theory: all pipes <15% busy + Occupancy ~10% (~1.3 blocks/CU) =>
// the kernel is CONCURRENCY-bound, not schedule/throughput-bound (3 schedule
// rewrites were null). Raise co-residency to 3 blocks/CU (12 waves):
//   BK=64 -> LDS 32 KB/block (dbuf), K=32 fp8 MFMA (2-VGPR frags) +
//   __launch_bounds__(256,3) -> <=168 VGPR -> 3 waves/SIMD.
// Frag-packed Fn layout: staging = linear copy, frag reads conflict-free.
// Epilogue: NO global atomics. Block (bi,bj) owns slot bj for row-partials and
// slot bi for col-partials -> exact disjoint cover of P[f][u][slot][g].
__global__ __launch_bounds__(256, 3) void sim_kernel(const unsigned char* __restrict__ F,
                                                     const int* __restrict__ label,
                                                     float* __restrict__ P) {
    // band tables: bj in [bs[x], be[x]); bn[x] = tiles in band
    const int bs[8] = {0, 23, 32, 40, 46, 51, 56, 60};
    const int be[8] = {23, 32, 40, 46, 51, 56, 60, 64};
    const int bn[8] = {276, 252, 292, 261, 245, 270, 234, 250};

    const int x = blockIdx.x & 7;       // XCD (round-robin dispatch heuristic)
    const int l = blockIdx.x >> 3;      // local index within band
    if (l >= bn[x]) return;             // padding block

    const int s = bs[x];
    const int w = be[x] - s;
    int bi, bj;
    const int nfull = s * w;
    if (l < nfull) {
        bi = l / w;
        bj = s + (l % w);
    } else {
        int l2 = l - nfull;
        int k = 0, width = w;
        while (l2 >= width) { l2 -= width; --width; ++k; }
        bi = s + k;
        bj = bi + l2;
    }
    const bool diag = (bi == bj);

    const int f = blockIdx.z;
    const int rowTile = bi * 128;
    const int colTile = bj * 128;

    // two 8-KB image buffers per operand (double buffer), linear layout.
    __shared__ __align__(16) unsigned char As[2][SBUF];
    __shared__ __align__(16) unsigned char Bs[2][SBUF];

    const int tid  = threadIdx.x;
    const int lane = tid & 63;
    const int wave = tid >> 6;
    const int wm   = wave >> 1;        // 2x2 wave grid over the 128x128 tile
    const int wn   = wave & 1;
    const int quad = lane >> 4;
    const int cl   = lane & 15;

    // staging: per K-block each wave copies 2 KB of A and 2 KB of B
    // (2+2 global_load_lds of 1 KB contiguous each; pure linear copy).
    const unsigned char* gA = F + (size_t)f * FSZ + (size_t)bi * OPB + wave * 2048 + lane * 16;
    const unsigned char* gB = F + (size_t)f * FSZ + (size_t)bj * OPB + wave * 2048 + lane * 16;
    unsigned char* lA = As[0] + wave * 2048 + lane * 16;
    unsigned char* lB = Bs[0] + wave * 2048 + lane * 16;

    floatx4 acc[4][4];
    const floatx4 z4 = {0.f, 0.f, 0.f, 0.f};
    #pragma unroll
    for (int mi = 0; mi < 4; ++mi)
        #pragma unroll
        for (int ni = 0; ni < 4; ++ni) acc[mi][ni] = z4;

    // frag read base: lane (q,cl) reads b128 at group*1024 + q*256 + cl*16;
    // the 16 B = (k-lo 8 B || k-hi 8 B) for the two K=32 MFMA steps.
    const unsigned char* aF = As[0] + quad * 256 + cl * 16;
    const unsigned char* bF = Bs[0] + quad * 256 + cl * 16;

    // ---- prologue: stage K-block 0 into buffer 0 (4 loads/wave in flight) ----
    #pragma unroll
    for (int t = 0; t < 2; ++t) {
        async_ld16(gA + (size_t)t * 1024, lA + t * 1024);
        async_ld16(gB + (size_t)t * 1024, lB + t * 1024);
    }
    gA += PAN; gB += PAN;

    #pragma unroll
    for (int kb = 0; kb < 16; ++kb) {
        const int cur = kb & 1;
        const int nxt = cur ^ 1;
        if (kb < 15) {
            // prefetch K-block kb+1 into the buffer not read this iteration
            #pragma unroll
            for (int t = 0; t < 2; ++t) {
                async_ld16(gA + (size_t)t * 1024, lA + nxt * SBUF + t * 1024);
                async_ld16(gB + (size_t)t * 1024, lB + nxt * SBUF + t * 1024);
            }
            gA += PAN; gB += PAN;
            asm volatile("s_waitcnt vmcnt(4)" ::: "memory");   // this wave's kb loads
        } else {
            asm volatile("s_waitcnt vmcnt(0)" ::: "memory");
        }
        __builtin_amdgcn_s_barrier();        // all waves' kb data in LDS
        __builtin_amdgcn_sched_barrier(0);   // keep ds_reads below the barrier

        longx2 bfr[4];
        #pragma unroll
        for (int ni = 0; ni < 4; ++ni)
            bfr[ni] = as_l2(*(const intx4*)(bF + cur * SBUF + (wn * 4 + ni) * 1024));
        __builtin_amdgcn_s_setprio(1);
        #pragma unroll
        for (int mi = 0; mi < 4; ++mi) {
            longx2 afr = as_l2(*(const intx4*)(aF + cur * SBUF + (wm * 4 + mi) * 1024));
            #pragma unroll
            for (int ni = 0; ni < 4; ++ni) {
                acc[mi][ni] = __builtin_amdgcn_mfma_f32_16x16x32_fp8_fp8(
                    afr[0], bfr[ni][0], acc[mi][ni], 0, 0, 0);
                acc[mi][ni] = __builtin_amdgcn_mfma_f32_16x16x32_fp8_fp8(
                    afr[1], bfr[ni][1], acc[mi][ni], 0, 0, 0);
            }
        }
        __builtin_amdgcn_s_setprio(0);
        __builtin_amdgcn_sched_barrier(0);   // keep reads/MFMA above the barrier
        __builtin_amdgcn_s_barrier();        // buf[cur] free for next prefetch
    }

    // ---- epilogue: e = exp(acc * EXPF), eye mask, block-local LDS
    //      reduction, then conflict-free partial-sum stores (no atomics) ----
    __syncthreads();                      // all frag reads done; As reusable
    float* red = (float*)As;              // 4 KB needed, 16 KB available
    // layout (floats): [0..256)   rowR, indexed wn*128 + rowLoc
    //                  [256..512) rowN
    //                  [512..768) colR, indexed wm*128 + colLoc
    //                  [768..1024) colN
    // every entry written by exactly one lane -> plain ds_write, no init.

    int   colg[4], colLoc[4];
    float wRc[4];                        // col label weight (row-part bucket)
    #pragma unroll
    for (int ni = 0; ni < 4; ++ni) {
        colLoc[ni] = wn * 64 + ni * 16 + cl;
        colg[ni]   = colTile + colLoc[ni];
        wRc[ni]    = (label[colg[ni]] != 0) ? 1.0f : 0.0f;
    }

    float colR[4] = {0.f, 0.f, 0.f, 0.f};
    float colN[4] = {0.f, 0.f, 0.f, 0.f};

    #pragma unroll
    for (int mi = 0; mi < 4; ++mi) {
        const int rowLocB = wm * 64 + mi * 16 + quad * 4;   // C/D: row=quad*4+reg
        #pragma unroll
        for (int r = 0; r < 4; ++r) {
            const int rowLoc = rowLocB + r;
            const int rowg   = rowTile + rowLoc;
            const float wRr  = (label[rowg] != 0) ? 1.0f : 0.0f;
            float pR = 0.f, pN = 0.f;
            #pragma unroll
            for (int ni = 0; ni < 4; ++ni) {
                float c = acc[mi][ni][r];
                float e = __expf(c * EXPF);
                if (diag) e = (rowg == colg[ni]) ? 0.0f : e;      // eye mask
                pR += wRc[ni] * e;
                pN += (1.0f - wRc[ni]) * e;
                colR[ni] += wRr * e;
                colN[ni] += (1.0f - wRr) * e;
            }
            #pragma unroll
            for (int m = 1; m < 16; m <<= 1) {
                pR += __shfl_xor(pR, m);
                pN += __shfl_xor(pN, m);
            }
            if (cl == 0) {
                red[wn * 128 + rowLoc]       = pR;
                red[256 + wn * 128 + rowLoc] = pN;
            }
        }
    }

    if (!diag) {
        #pragma unroll
        for (int ni = 0; ni < 4; ++ni) {
            float cR = colR[ni], cN = colN[ni];
            cR += __shfl_xor(cR, 16); cN += __shfl_xor(cN, 16);
            cR += __shfl_xor(cR, 32); cN += __shfl_xor(cN, 32);
            if (quad == 0) {
                red[512 + wm * 128 + colLoc[ni]] = cR;
                red[768 + wm * 128 + colLoc[ni]] = cN;
            }
        }
    }

    __syncthreads();
    // P layout: [f][u(R=0,N=1)][slot 0..63][g 0..8191]
    float* Pr = P + ((size_t)f * 2 + 0) * (size_t)NTILE * BATCH;
    float* Pn = P + ((size_t)f * 2 + 1) * (size_t)NTILE * BATCH;
    if (tid < 128) {
        Pr[(size_t)bj * BATCH + rowTile + tid] = red[tid]       + red[128 + tid];
        Pn[(size_t)bj * BATCH + rowTile + tid] = red[256 + tid] + red[384 + tid];
        if (!diag) {
            Pr[(size_t)bi * BATCH + colTile + tid] = red[512 + tid] + red[640 + tid];
            Pn[(size_t)bi * BATCH + colTile + tid] = red[768 + tid] + red[896 + tid];
        }
    }
}

// -------- final: 64-slot partial reduce + per-row loss + global reduce --------
__global__ __launch_bounds__(256) void loss_kernel(const float* __restrict__ P,
                                                   const int* __restrict__ label,
                                                   float* __restrict__ out) {
    const int idx = blockIdx.x * 256 + threadIdx.x;   // 0..16383 = (f, i)
    const int f = idx >> 13;
    const int i = idx & (BATCH - 1);
    const int lab = label[i];
    const float* Pr = P + ((size_t)f * 2 + 0) * (size_t)NTILE * BATCH;
    const float* Pn = Pr + (size_t)NTILE * BATCH;
    float sR = 0.f, sN = 0.f;
    #pragma unroll 8
    for (int s = 0; s < NTILE; ++s) {
        sR += Pr[(size_t)s * BATCH + i];
        sN += Pn[(size_t)s * BATCH + i];
    }
    const float own = lab ? sR : sN;
    const float oth = lab ? sN : sR;
    float t = -logf(own / (own + oth) + 1e-8f) * (1.0f / 4096.0f);
    #pragma unroll
    for (int m = 32; m >= 1; m >>= 1) t += __shfl_xor(t, m);
    __shared__ float red[4];
    if ((threadIdx.x & 63) == 0) red[threadIdx.x >> 6] = t;
    __syncthreads();
    if (threadIdx.x == 0) atomicAdd(out, red[0] + red[1] + red[2] + red[3]);
}

extern "C" void kernel_launch(void* const* d_in, const int* in_sizes, int n_in,
                              void* d_out, int out_size, void* d_ws, size_t ws_size,
                              hipStream_t stream) {
    const float* text  = (const float*)d_in[0];
    const float* image = (const float*)d_in[1];
    const int*   label = (const int*)d_in[2];
    float* out = (float*)d_out;

    // workspace: Fn[2][16][64][8192] fp8 (16 MB), then P[2][2][64][8192] f32 (16 MB)
    unsigned char* Fn = (unsigned char*)d_ws;
    float* P = (float*)((char*)d_ws + (size_t)2 * BATCH * DIM);

    hipMemsetAsync(out, 0, sizeof(float), stream);

    dim3 ngrid(BATCH, 2);
    norm_kernel<<<ngrid, 256, 0, stream>>>(text, image, Fn);

    dim3 grid(GRIDX, 1, 2);
    sim_kernel<<<grid, 256, 0, stream>>>(Fn, label, P);

    loss_kernel<<<(2 * BATCH) / 256, 256, 0, stream>>>(P, label, out);
}